// Round 13
// baseline (129.713 us; speedup 1.0000x reference)
//
#include <hip/hip_runtime.h>
#include <math.h>

// Problem constants
#define R_ 5
#define NN 68        // N_NODES == LATENT
#define KK 32        // neighbors per node
#define NL 3         // GCN layers
#define LAT 68
#define NSL 17               // nodes per wave slice (4 waves x 17 = 68)
#define ROWQ (NN / 4)        // 17 float4 per node row
#define NF4 ((NN * NN) / 4)  // 1156 float4 per output row
#define BBK2 16              // batches per K2 block
#define LSTR 344             // LDS row stride (floats) for K2, 16B-aligned
#define NPREP (R_ * NL)      // 15 densify blocks inside prep_k

// ---------------- P: merged prep (densify + z-transpose) ----------------
__global__ __launch_bounds__(256) void prep_k(
    const float* __restrict__ z, const int* __restrict__ adj,
    const float* __restrict__ gw, float* __restrict__ wd,
    float* __restrict__ zT, int B) {
  const int t = threadIdx.x;
  if (blockIdx.x < NPREP) {
    const int rl = blockIdx.x;  // r*NL + l
    __shared__ float col[NN][NN + 4];
    for (int i = t; i < NN * (NN + 4); i += 256) (&col[0][0])[i] = 0.0f;
    __syncthreads();
    if (t < NN) {
      const int n = t;  // thread owns column n -> no races
      const int* ar = adj + n * KK;
      const float* wr = gw + ((size_t)rl * NN + n) * KK;
      for (int k = 0; k < KK; ++k) col[ar[k]][n] += wr[k];
    }
    __syncthreads();
    float* wout = wd + (size_t)rl * NN * NN;  // [m][n], n contiguous
    for (int i = t; i < NN * NN; i += 256) {
      const int m = i / NN, n = i - m * NN;
      wout[i] = col[m][n];
    }
  } else {
    const int b0 = (blockIdx.x - NPREP) * 64;
    __shared__ float zls[64][LAT + 1];  // +1: stride 69, conflict-free
    for (int idx = t; idx < 64 * ROWQ; idx += 256) {
      const int row = idx / ROWQ, q = idx - row * ROWQ;
      const float4 v =
          *reinterpret_cast<const float4*>(z + (size_t)(b0 + row) * LAT + 4 * q);
      zls[row][4 * q + 0] = v.x;
      zls[row][4 * q + 1] = v.y;
      zls[row][4 * q + 2] = v.z;
      zls[row][4 * q + 3] = v.w;
    }
    __syncthreads();
    for (int idx = t; idx < LAT * 64; idx += 256) {
      const int l = idx >> 6, bb = idx & 63;
      zT[(size_t)l * B + b0 + bb] = zls[bb][l];
    }
  }
}

// ---------------- K1: GEMM-chain (v12 verbatim — chunked m, s_load path) ---
__global__ __launch_bounds__(256) void chain_k(
    const float* __restrict__ zT, const float* __restrict__ fc_w,
    const float* __restrict__ fc_b, const float* __restrict__ wd,
    const float* __restrict__ gb, float* __restrict__ X, int B, int nb) {
  const int t = threadIdx.x;
  const int lane = t & 63;
  const int w = __builtin_amdgcn_readfirstlane(t >> 6);
  const int n0 = w * NSL;  // first node of this wave's slice (wave-uniform)
  const int r = blockIdx.x / nb;
  const int b0 = (blockIdx.x - r * nb) * 64;

  __shared__ float xs[NN][64];  // 17.4 KB; z, then x, per stage

  for (int idx = t; idx < NN * 64; idx += 256) {
    const int m = idx >> 6;
    xs[m][idx & 63] = zT[(size_t)m * B + b0 + (idx & 63)];
  }
  __syncthreads();

  float acc[NSL];

#pragma unroll 1
  for (int stage = 0; stage < 1 + NL; ++stage) {
    const float* wb = (stage == 0) ? fc_w + (size_t)r * LAT * NN
                                   : wd + (size_t)(r * NL + stage - 1) * NN * NN;
    const float* bias = (stage == 0) ? fc_b + r * NN
                                     : gb + (size_t)(r * NL + stage - 1) * NN;
#pragma unroll
    for (int j = 0; j < NSL; ++j) acc[j] = bias[n0 + j];  // uniform -> s_load

#pragma unroll 1
    for (int mb = 0; mb < 4; ++mb) {  // 4 chunks of 17 rows
      float xmv[NSL];                 // statically indexed -> stays in VGPRs
#pragma unroll
      for (int k = 0; k < NSL; ++k) xmv[k] = xs[mb * NSL + k][lane];
      const float* wrb = wb + (size_t)(mb * NSL) * NN + n0;
#pragma unroll
      for (int k = 0; k < NSL; ++k) {
        const float* wr = wrb + (size_t)k * NN;  // wave-uniform -> s_load
#pragma unroll
        for (int j = 0; j < NSL; ++j) acc[j] = fmaf(xmv[k], wr[j], acc[j]);
      }
    }
    if (stage > 0) {
#pragma unroll
      for (int j = 0; j < NSL; ++j)
        acc[j] = 1.0f / (1.0f + __expf(-acc[j]));
    }
    if (stage < NL) {
      __syncthreads();  // everyone done READING xs for this stage
#pragma unroll
      for (int j = 0; j < NSL; ++j) xs[n0 + j][lane] = acc[j];
      __syncthreads();
    }
  }

  // ---- final X -> ws, layout [r*68+n][b]: coalesced 256B rows ----
  float* Xb = X + ((size_t)r * NN + n0) * B + b0 + lane;
#pragma unroll
  for (int j = 0; j < NSL; ++j) Xb[(size_t)j * B] = acc[j];
}

// ---------------- K2: outer product, reg-tiled + wave-private obuf ---------
// Compute (v8-style register reuse): lane -> (bsub = lane>>4, c = lane&15),
// bb = wv*4+bsub; xj[r] preloaded once, xi[r] one broadcast b128 per r per
// 4-row group. Each wave stages its 4 batches x 4 rows x 68 floats in its
// PRIVATE obuf slice (no __syncthreads — DS ops are in-order per wave, the
// compiler's lgkmcnt covers the RAW), then copies linearly: every store
// segment is a multiple of 4 f4 at 4-f4-aligned offsets (68 % 4 == 0) ->
// full 64B lines only, 1KB/instr for 4 of 5 copy iterations.
__global__ __launch_bounds__(256) void outer_k(const float* __restrict__ X,
                                               float* __restrict__ out, int B) {
  const int t = threadIdx.x;
  const int b0 = blockIdx.x * BBK2;
  __shared__ float xls[BBK2 * LSTR];   // 22.0 KB
  __shared__ float obuf[4][4 * 272];   // 17.4 KB: per-wave 4 batches x 272

  // stage X[rn][b0..b0+15] -> xls[bb][rn]; reads are exact 64B lines
  for (int idx = t; idx < R_ * NN * BBK2; idx += 256) {
    const int rn = idx >> 4, bb = idx & (BBK2 - 1);
    xls[bb * LSTR + rn] = X[(size_t)rn * B + b0 + bb];
  }
  __syncthreads();

  const int lane = t & 63;
  const int wv = t >> 6;
  const int bsub = lane >> 4;           // batch within wave (0..3)
  const int bb = wv * 4 + bsub;         // 0..15
  const int c = lane & 15;              // f4-col 0..15; c==0 lane also col 16
  const float* xb = &xls[bb * LSTR];

  float4 xj[R_], xj16[R_];
#pragma unroll
  for (int r = 0; r < R_; ++r)
    xj[r] = *reinterpret_cast<const float4*>(xb + r * NN + 4 * c);
#pragma unroll
  for (int r = 0; r < R_; ++r)
    xj16[r] = *reinterpret_cast<const float4*>(xb + r * NN + 64);

  float* ow = &obuf[wv][0];             // wave-private 1088 floats
  const float4* ow4 = reinterpret_cast<const float4*>(ow);  // 272 f4
  float4* out4 = reinterpret_cast<float4*>(out);

#pragma unroll 1
  for (int g = 0; g < 17; ++g) {  // rows i = 4g..4g+3
    float4 xi[R_];
#pragma unroll
    for (int r = 0; r < R_; ++r)
      xi[r] = *reinterpret_cast<const float4*>(xb + r * NN + 4 * g);  // bcast
#pragma unroll
    for (int k = 0; k < 4; ++k) {
      float4 a = make_float4(0.f, 0.f, 0.f, 0.f);
#pragma unroll
      for (int r = 0; r < R_; ++r) {
        const float s = reinterpret_cast<const float*>(&xi[r])[k];  // static k
        a.x = fmaf(s, xj[r].x, a.x);
        a.y = fmaf(s, xj[r].y, a.y);
        a.z = fmaf(s, xj[r].z, a.z);
        a.w = fmaf(s, xj[r].w, a.w);
      }
      *reinterpret_cast<float4*>(&ow[bsub * 272 + k * NN + 4 * c]) = a;
      if (c == 0) {  // edge f4-column 16 (cols 64..67)
        float4 e = make_float4(0.f, 0.f, 0.f, 0.f);
#pragma unroll
        for (int r = 0; r < R_; ++r) {
          const float s = reinterpret_cast<const float*>(&xi[r])[k];
          e.x = fmaf(s, xj16[r].x, e.x);
          e.y = fmaf(s, xj16[r].y, e.y);
          e.z = fmaf(s, xj16[r].z, e.z);
          e.w = fmaf(s, xj16[r].w, e.w);
        }
        *reinterpret_cast<float4*>(&ow[bsub * 272 + k * NN + 64]) = e;
      }
    }
    // wave-private copy: 272 f4 -> out rows 4g..4g+3 of this wave's 4 batches
    // (no barrier; in-wave DS ordering + compiler lgkmcnt handle the RAW)
#pragma unroll
    for (int j = 0; j < 5; ++j) {
      const int idx = j * 64 + lane;          // f4 index in wave chunk
      if (idx < 272) {
        const int bs2 = idx / 68;             // batch sub (magic-mul)
        const int rem = idx - bs2 * 68;       // f4 within 4-row group
        out4[(size_t)(b0 + wv * 4 + bs2) * NF4 + g * 68 + rem] = ow4[idx];
      }
    }
  }
}

extern "C" void kernel_launch(void* const* d_in, const int* in_sizes, int n_in,
                              void* d_out, int out_size, void* d_ws, size_t ws_size,
                              hipStream_t stream) {
  const float* z    = (const float*)d_in[0];  // (16384, 68)
  const int*   adj  = (const int*)  d_in[1];  // (68, 32)
  const float* fc_w = (const float*)d_in[2];  // (5, 68, 68)
  const float* fc_b = (const float*)d_in[3];  // (5, 68)
  const float* gw   = (const float*)d_in[4];  // (5, 3, 68, 32)
  const float* gb   = (const float*)d_in[5];  // (5, 3, 68)
  float* out = (float*)d_out;                 // (16384, 4624)

  const int B = in_sizes[0] / LAT;            // 16384
  // ws layout (f32): wd[15*68*68] | zT[68*B] | X[340*B]  (~27.1 MB total)
  float* wd = (float*)d_ws;
  float* zT = wd + R_ * NL * NN * NN;
  float* X  = zT + (size_t)LAT * B;

  const int nb = B / 64;                      // 256 batch-groups (chain)

  prep_k<<<NPREP + B / 64, 256, 0, stream>>>(z, adj, gw, wd, zT, B);
  chain_k<<<R_ * nb, 256, 0, stream>>>(zT, fc_w, fc_b, wd, gb, X, B, nb);
  outer_k<<<B / BBK2, 256, 0, stream>>>(X, out, B);
}